// Round 11
// baseline (654.540 us; speedup 1.0000x reference)
//
#include <hip/hip_runtime.h>
#include <hip/hip_bf16.h>
#include <math.h>

#define N_NODES 20000
#define N_EDGES 320000
#define HID 50
#define XS 64     // row stride (ushorts) for all bf16 node/edge state -> 128 B, 16B-aligned

typedef short bf16x8 __attribute__((ext_vector_type(8)));
typedef float f32x4 __attribute__((ext_vector_type(4)));

__device__ inline ushort f2bf(float f) {
    __hip_bfloat16 h = __float2bfloat16(f);
    union { __hip_bfloat16 h; ushort u; } c; c.h = h; return c.u;
}
__device__ inline uint pack2(float a, float b) {
    return (uint)f2bf(a) | ((uint)f2bf(b) << 16);
}

// LDS-only barrier: waits LDS ops, does NOT drain vmcnt -> global loads,
// stores and atomics stay in flight across tiles (T4). sched_barrier(0)
// fences the machine scheduler on both sides (rule #18).
__device__ inline void lds_barrier() {
    asm volatile("s_waitcnt lgkmcnt(0)" ::: "memory");
    __builtin_amdgcn_sched_barrier(0);
    __builtin_amdgcn_s_barrier();
    __builtin_amdgcn_sched_barrier(0);
    asm volatile("" ::: "memory");
}

// ---------------------------------------------------------------------------
// Edge sorting by dst: histogram -> single-block scan -> atomic scatter.
// ---------------------------------------------------------------------------
__global__ __launch_bounds__(256) void hist_kernel(const int* __restrict__ dst, int* __restrict__ cnt) {
    const int e = blockIdx.x * 256 + threadIdx.x;
    if (e < N_EDGES) atomicAdd(&cnt[dst[e]], 1);
}

__global__ __launch_bounds__(1024) void scan_kernel(const int* __restrict__ cnt, int* __restrict__ offs) {
    __shared__ int part[1024];
    const int t = threadIdx.x;
    int loc[20]; int s = 0;
    #pragma unroll
    for (int i = 0; i < 20; ++i) {
        const int idx = t * 20 + i;
        const int v = (idx < N_NODES) ? cnt[idx] : 0;
        loc[i] = s; s += v;
    }
    part[t] = s; __syncthreads();
    for (int off = 1; off < 1024; off <<= 1) {
        const int v = (t >= off) ? part[t - off] : 0;
        __syncthreads();
        part[t] += v;
        __syncthreads();
    }
    const int ex = (t > 0) ? part[t - 1] : 0;
    #pragma unroll
    for (int i = 0; i < 20; ++i) {
        const int idx = t * 20 + i;
        if (idx < N_NODES) offs[idx] = ex + loc[i];
    }
}

__global__ __launch_bounds__(256) void scatter_kernel(const int* __restrict__ src, const int* __restrict__ dst,
        int* __restrict__ offs, int* __restrict__ perm,
        int* __restrict__ sdst_p, int* __restrict__ ssrc_p) {
    const int e = blockIdx.x * 256 + threadIdx.x;
    if (e >= N_EDGES) return;
    const int d = dst[e];
    const int pos = atomicAdd(&offs[d], 1);
    perm[pos] = e;
    sdst_p[pos] = d;
    ssrc_p[pos] = src[e];
}

__global__ __launch_bounds__(256) void xconv_kernel(const float* __restrict__ x, ushort* __restrict__ xb1) {
    const int i = blockIdx.x * 256 + threadIdx.x;
    if (i < N_NODES * 64) xb1[i] = f2bf(x[i]);   // XS==64 == feature count: dense
}

// ---------------------------------------------------------------------------
// Build W^T bf16 [128][Kpad], section layout: orig W rows [0,F) -> k 0..,
// [F,2F) -> k 64.., [2F,2F+FE) -> k 128..; other k rows are ZERO.
// cols 0..49 = Wm, cols 64..113 = We, rest 0. bc[128] = fused bias.
// ---------------------------------------------------------------------------
__global__ __launch_bounds__(256) void prep_w_kernel(
    const float* __restrict__ Wm, const float* __restrict__ We,
    const float* __restrict__ bm, const float* __restrict__ be,
    ushort* __restrict__ Wt, float* __restrict__ bc, int F, int FE, int Kpad)
{
    const int l = blockIdx.y;
    const int K = 2 * F + FE;
    const float* Wm_l = Wm + (size_t)l * K * HID;
    const float* We_l = We + (size_t)l * K * HID;
    const float* bm_l = bm + (size_t)l * HID;
    const float* be_l = be + (size_t)l * HID;
    ushort* Wt_l = Wt + (size_t)l * 128 * Kpad;
    float*  bc_l = bc + (size_t)l * 128;
    for (int idx = blockIdx.x * 256 + threadIdx.x; idx < 128 * Kpad; idx += gridDim.x * 256) {
        const int c = idx / Kpad;
        const int k = idx - c * Kpad;
        int r = -1;
        if (k < 64)       { if (k < F)        r = k; }
        else if (k < 128) { if (k - 64 < F)   r = F + (k - 64); }
        else              { if (k - 128 < FE) r = 2 * F + (k - 128); }
        float v = 0.f;
        if (r >= 0) {
            if (c < HID)                      v = Wm_l[(size_t)r * HID + c];
            else if (c >= 64 && c < 64 + HID) v = We_l[(size_t)r * HID + (c - 64)];
        }
        Wt_l[(size_t)c * Kpad + k] = f2bf(v);
        if (k == 0) {
            float b = 0.f;
            if (c < HID)                      b = bm_l[c];
            else if (c >= 64 && c < 64 + HID) b = be_l[c - 64];
            bc_l[c] = b;
        }
    }
}

// ---------------------------------------------------------------------------
// Persistent pipelined MFMA message+edge-update kernel (round-9 structure,
// ET now templated). Per tile: compute -> out->LDS -> [lds_barrier]
//   -> write_stage(t+G) -> issue(t+2G) -> e-stores -> seg-sum atomics
//   -> [lds_barrier]. Barriers wait ONLY on lgkmcnt (vmem stays in flight).
// ---------------------------------------------------------------------------
template<int NCH, int ET, bool L1>
__global__ __launch_bounds__(256) void msg_mfma_kernel(
    const ushort* __restrict__ xb,       // bf16 node features, row stride XS
    const float*  __restrict__ ea,       // L1: fp32 [E][112] (original order)
    const ushort* __restrict__ ein,      // !L1: bf16 [E][XS] (sorted order)
    const int*    __restrict__ perm,     // L1: sorted -> original edge id
    ushort* __restrict__ eout,           // bf16 [E][XS] (sorted order)
    const int* __restrict__ sdst_idx, const int* __restrict__ ssrc_idx,  // sorted
    const ushort* __restrict__ Wt,       // bf16 [128][NCH*32]
    const float* __restrict__ bc,        // [128]
    float* __restrict__ xo)
{
    constexpr int KPAD = NCH * 32;       // ushorts per h row
    constexpr int KPS  = KPAD + 8;       // +16B pad (row stride still 16B-aligned)
    constexpr int NT   = N_EDGES / ET;
    constexpr int MT   = ET / 16;        // M-tiles per wave
    constexpr int NR   = ET / 32;        // staged rows per thread

    __shared__ __align__(16) ushort hl[ET * KPS];
    __shared__ __align__(16) float  xol[ET * 52];
    __shared__ __align__(16) ushort epack[ET * 72];
    __shared__ int sdst_s[2][ET];
    __shared__ int segs[ET + 2];
    __shared__ int nseg_s;

    const int t = threadIdx.x;
    const int lane = t & 63, w = t >> 6;
    const int r = t >> 3, ch0 = t & 7;         // staging row / 16B-chunk
    const int row16 = lane & 15, g = lane >> 4;
    const int G = gridDim.x;

    // staged registers (data for a future tile)
    int sd[NR], ss[NR], pm[NR];
    bf16x8 Rd[NR], Rs[NR], Re[NR];
    float4 P0a, P0b, P1a, P1b;           // L1 only (NR==1 there)

    auto issue = [&](int tl) {
        #pragma unroll
        for (int i = 0; i < NR; ++i) {
            const int eb = tl * ET + i * 32;
            sd[i] = sdst_idx[eb + r];
            ss[i] = ssrc_idx[eb + r];
            if constexpr (L1) pm[i] = perm[eb + r];
        }
        #pragma unroll
        for (int i = 0; i < NR; ++i) {
            Rd[i] = *(const bf16x8*)(xb + (size_t)sd[i] * XS + ch0 * 8);
            Rs[i] = *(const bf16x8*)(xb + (size_t)ss[i] * XS + ch0 * 8);
            if constexpr (L1) {
                const float* pe = ea + (size_t)pm[i] * 112;
                P0a = *(const float4*)(pe + 8 * ch0);
                P0b = *(const float4*)(pe + 8 * ch0 + 4);
                if (ch0 < 6) {
                    P1a = *(const float4*)(pe + 8 * (ch0 + 8));
                    P1b = *(const float4*)(pe + 8 * (ch0 + 8) + 4);
                }
            } else {
                Re[i] = *(const bf16x8*)(ein + ((size_t)tl * ET + i * 32 + r) * XS + ch0 * 8);
            }
        }
    };

    auto write_stage = [&](int par) {
        #pragma unroll
        for (int i = 0; i < NR; ++i) {
            const int row = r + i * 32;
            *(bf16x8*)&hl[row * KPS + ch0 * 8]      = Rd[i];
            *(bf16x8*)&hl[row * KPS + 64 + ch0 * 8] = Rs[i];
            if constexpr (L1) {
                union { bf16x8 v; uint u[4]; } c0;
                c0.u[0] = pack2(P0a.x, P0a.y); c0.u[1] = pack2(P0a.z, P0a.w);
                c0.u[2] = pack2(P0b.x, P0b.y); c0.u[3] = pack2(P0b.z, P0b.w);
                *(bf16x8*)&hl[row * KPS + 128 + ch0 * 8] = c0.v;
                if (ch0 < 6) {
                    union { bf16x8 v; uint u[4]; } c1;
                    c1.u[0] = pack2(P1a.x, P1a.y); c1.u[1] = pack2(P1a.z, P1a.w);
                    c1.u[2] = pack2(P1b.x, P1b.y); c1.u[3] = pack2(P1b.z, P1b.w);
                    *(bf16x8*)&hl[row * KPS + 192 + ch0 * 8] = c1.v;
                } else {
                    *(bf16x8*)&hl[row * KPS + 192 + ch0 * 8] = (bf16x8){0,0,0,0,0,0,0,0};
                }
            } else {
                *(bf16x8*)&hl[row * KPS + 128 + ch0 * 8] = Re[i];
            }
            if (ch0 == 0) sdst_s[par][row] = sd[i];
        }
    };

    int tile = blockIdx.x;
    if (tile >= NT) return;

    const int colA = (2 * w) * 16 + row16;
    const int colB = colA + 16;
    const float bA = bc[colA], bB = bc[colB];
    const ushort* wpA = Wt + (size_t)colA * KPAD + 8 * g;
    const ushort* wpB = Wt + (size_t)colB * KPAD + 8 * g;

    // hoisted W fragments for the K150 layers (48 VGPR at NCH=6)
    bf16x8 BfA[NCH], BfB[NCH];
    if constexpr (!L1) {
        #pragma unroll
        for (int c = 0; c < NCH; ++c) {
            BfA[c] = *(const bf16x8*)(wpA + c * 32);
            BfB[c] = *(const bf16x8*)(wpB + c * 32);
        }
    }

    // prologue: stage first tile; issue loads for the second
    issue(tile);
    write_stage(0);
    if (tile + G < NT) issue(tile + G);
    __syncthreads();

    int par = 0;
    for (; tile < NT; tile += G) {
        // ---- compute: each wave owns col-tiles {2w, 2w+1} over MT M-tiles ----
        f32x4 accA[MT], accB[MT];
        #pragma unroll
        for (int m = 0; m < MT; ++m) {
            accA[m] = (f32x4){bA, bA, bA, bA};
            accB[m] = (f32x4){bB, bB, bB, bB};
        }
        #pragma unroll
        for (int c = 0; c < NCH; ++c) {
            bf16x8 a[MT];
            #pragma unroll
            for (int m = 0; m < MT; ++m)
                a[m] = *(const bf16x8*)&hl[(m * 16 + row16) * KPS + c * 32 + 8 * g];
            bf16x8 B0, B1;
            if constexpr (L1) {
                B0 = *(const bf16x8*)(wpA + c * 32);
                B1 = *(const bf16x8*)(wpB + c * 32);
            } else {
                B0 = BfA[c];
                B1 = BfB[c];
            }
            #pragma unroll
            for (int m = 0; m < MT; ++m) {
                accA[m] = __builtin_amdgcn_mfma_f32_16x16x32_bf16(a[m], B0, accA[m], 0, 0, 0);
                accB[m] = __builtin_amdgcn_mfma_f32_16x16x32_bf16(a[m], B1, accB[m], 0, 0, 0);
            }
        }

        // ---- write outputs to LDS scratch ----
        if (w < 2) {
            #pragma unroll
            for (int m = 0; m < MT; ++m) {
                #pragma unroll
                for (int rr = 0; rr < 4; ++rr) {
                    const int row = m * 16 + 4 * g + rr;
                    if (colA < HID) xol[row * 52 + colA] = accA[m][rr];
                    if (colB < HID) xol[row * 52 + colB] = accB[m][rr];
                }
            }
        } else {
            const int lcA = colA - 64, lcB = colB - 64;
            #pragma unroll
            for (int m = 0; m < MT; ++m) {
                #pragma unroll
                for (int rr = 0; rr < 4; ++rr) {
                    const int row = m * 16 + 4 * g + rr;
                    epack[row * 72 + lcA] = f2bf(accA[m][rr]);
                    epack[row * 72 + lcB] = f2bf(accB[m][rr]);
                }
            }
        }

        // ---- wave 0: segment boundaries of sorted dst ----
        if (w == 0) {
            if constexpr (ET == 64) {
                const int dl = sdst_s[par][lane];
                const int dp = sdst_s[par][lane > 0 ? lane - 1 : 0];
                const bool flag = (lane == 0) || (dl != dp);
                const unsigned long long bal = __ballot(flag);
                if (flag) segs[__popcll(bal & ((1ull << lane) - 1ull))] = lane;
                if (lane == 63) {
                    const int ns = __popcll(bal);
                    nseg_s = ns;
                    segs[ns] = 64;
                }
            } else {
                const int l31 = lane & 31;
                const int dl  = sdst_s[par][l31];
                const int dp  = sdst_s[par][l31 > 0 ? l31 - 1 : 0];
                const bool flag = (l31 == 0) || (dl != dp);
                const unsigned long long bal = __ballot(flag) & 0xFFFFFFFFull;
                if (lane < 32 && flag)
                    segs[__popcll(bal & ((1ull << l31) - 1ull))] = l31;
                if (lane == 0) {
                    const int ns = __popcll(bal);
                    nseg_s = ns;
                    segs[ns] = 32;
                }
            }
        }
        lds_barrier();   // B1: xol/epack/segs visible; hl reads done (LDS only)

        // ---- pipeline FIRST: ds_writes; staged regs are a full phase old ----
        if (tile + G < NT)     write_stage(par ^ 1);
        if (tile + 2 * G < NT) issue(tile + 2 * G);

        // ---- e-state full-row stores (all 64 cols; 50..63 are exact 0) ----
        #pragma unroll
        for (int i = 0; i < NR; ++i) {
            const int row = r + i * 32;
            const int4 v = *(const int4*)&epack[row * 72 + ch0 * 8];
            *(int4*)&eout[((size_t)tile * ET + row) * XS + ch0 * 8] = v;
        }
        // ---- segmented sum -> atomics (retire in next tile's shadow) ----
        const int ns = nseg_s;
        for (int idx = t; idx < ns * HID; idx += 256) {
            const int s = idx / HID, col = idx - s * HID;
            const int a0 = segs[s], b0 = segs[s + 1];
            float s0 = 0.f, s1 = 0.f, s2 = 0.f, s3 = 0.f;
            int rr = a0;
            for (; rr + 4 <= b0; rr += 4) {
                s0 += xol[(rr + 0) * 52 + col];
                s1 += xol[(rr + 1) * 52 + col];
                s2 += xol[(rr + 2) * 52 + col];
                s3 += xol[(rr + 3) * 52 + col];
            }
            for (; rr < b0; ++rr) s0 += xol[rr * 52 + col];
            atomicAdd(&xo[(size_t)sdst_s[par][a0] * HID + col], (s0 + s1) + (s2 + s3));
        }
        lds_barrier();   // B2: hl now holds tile+G (LDS only; vmem stays in flight)
        par ^= 1;
    }
}

// coalesced column stats: 80 blocks, contiguous 12500-elem span each,
// 250 threads x 50 iters (stride 250); partials -> atomics into sacc slot
__global__ __launch_bounds__(256) void stats_kernel(const float* __restrict__ xo,
                                                    float* __restrict__ sacc)
{
    __shared__ float sp[5][HID], sq[5][HID];
    const int t = threadIdx.x;
    if (t < 250) {
        float s = 0.f, q = 0.f;
        const size_t base = (size_t)blockIdx.x * 12500 + t;
        #pragma unroll
        for (int it = 0; it < 50; ++it) {
            const float v = xo[base + it * 250];
            s += v; q += v * v;
        }
        sp[t / HID][t % HID] = s;
        sq[t / HID][t % HID] = q;
    }
    __syncthreads();
    if (t < HID) {
        float s = 0.f, q = 0.f;
        #pragma unroll
        for (int p = 0; p < 5; ++p) { s += sp[p][t]; q += sq[p][t]; }
        atomicAdd(&sacc[t], s);
        atomicAdd(&sacc[HID + t], q);
    }
}

// BN(train) + ELU + residual; maintains bf16 mirror xb; zeroes xo for next layer
template<bool FIRST>
__global__ __launch_bounds__(256) void apply_kernel(float* __restrict__ xo,
    const float* __restrict__ sacc,
    const float* __restrict__ g, const float* __restrict__ b,
    float* __restrict__ cur, ushort* __restrict__ xb)
{
    const int i = blockIdx.x * 256 + threadIdx.x;
    if (i >= N_NODES * HID) return;
    const int c = i % HID;
    const float inv = 1.f / (float)N_NODES;
    const float mu = sacc[c] * inv;
    const float var = sacc[HID + c] * inv - mu * mu;
    const float z = (xo[i] - mu) * rsqrtf(var + 1e-5f) * g[c] + b[c];
    xo[i] = 0.f;                               // ready for next layer's atomics
    const float a = (z > 0.f) ? z : expm1f(z);
    const float nc = FIRST ? a : (cur[i] + a);
    cur[i] = nc;
    xb[(size_t)(i / HID) * XS + c] = f2bf(nc);
}

extern "C" void kernel_launch(void* const* d_in, const int* in_sizes, int n_in,
                              void* d_out, int out_size, void* d_ws, size_t ws_size,
                              hipStream_t stream)
{
    const float* x    = (const float*)d_in[0];
    const int*   ei   = (const int*)  d_in[1];
    const float* ea   = (const float*)d_in[2];
    const float* W1m  = (const float*)d_in[4];
    const float* b1m  = (const float*)d_in[5];
    const float* W1e  = (const float*)d_in[6];
    const float* b1e  = (const float*)d_in[7];
    const float* g1   = (const float*)d_in[8];
    const float* bt1  = (const float*)d_in[9];
    const float* Wm   = (const float*)d_in[10];
    const float* bm   = (const float*)d_in[11];
    const float* We   = (const float*)d_in[12];
    const float* be   = (const float*)d_in[13];
    const float* gam  = (const float*)d_in[14];
    const float* bet  = (const float*)d_in[15];

    float* out = (float*)d_out;

    char* ws = (char*)d_ws;
    ushort* e_ws   = (ushort*)(ws + 0);                      // [E][64] bf16   40,960,000
    float*  xo     = (float*) (ws + 40960000);               // [20000][50]     4,000,000
    float*  sacc   = (float*) (ws + 44960000);               // [10][128]           5,120
    ushort* Wt1    = (ushort*)(ws + 44965120);               // [128][256]         65,536
    float*  bc1    = (float*) (ws + 45030656);               // [128]                 512
    ushort* Wtk    = (ushort*)(ws + 45031168);               // [9][128][192]     442,368
    float*  bck    = (float*) (ws + 45473536);               // [9][128] + pad      5,120
    ushort* xb1    = (ushort*)(ws + 45478656);               // [20000][64]     2,560,000
    ushort* xb     = (ushort*)(ws + 48038656);               // [20000][64]     2,560,000
    int*    cnt    = (int*)   (ws + 50598656);               // [20000]            80,000
    int*    offs   = (int*)   (ws + 50678656);               // [20000]            80,000
    int*    perm   = (int*)   (ws + 50758656);               // [E]             1,280,000
    int*    sdst_p = (int*)   (ws + 52038656);               // [E]             1,280,000
    int*    ssrc_p = (int*)   (ws + 53318656);               // [E]             1,280,000

    const int* srcs = ei;
    const int* dsts = ei + N_EDGES;
    const int nApply = (N_NODES * HID + 255) / 256;

    // ---- one-time prep: sanitize state, sort edges by dst, convert, transpose ----
    hipMemsetAsync(xo, 0, 4005120, stream);                  // xo + sacc
    hipMemsetAsync(xb, 0, 2560000, stream);                  // pad cols of xb
    hipMemsetAsync(cnt, 0, N_NODES * sizeof(int), stream);
    hist_kernel<<<1250, 256, 0, stream>>>(dsts, cnt);
    scan_kernel<<<1, 1024, 0, stream>>>(cnt, offs);
    scatter_kernel<<<1250, 256, 0, stream>>>(srcs, dsts, offs, perm, sdst_p, ssrc_p);
    xconv_kernel<<<5000, 256, 0, stream>>>(x, xb1);
    prep_w_kernel<<<dim3(128, 1), 256, 0, stream>>>(W1m, W1e, b1m, b1e, Wt1, bc1, 64, 112, 256);
    prep_w_kernel<<<dim3(128, 9), 256, 0, stream>>>(Wm, We, bm, be, Wtk, bck, 50, 50, 192);

    // ---- layer 1: NCH=8, ET=32 (round-9 proven config); 5 blocks/CU ----
    msg_mfma_kernel<8, 32, true>
        <<<1280, 256, 0, stream>>>(xb1, ea, (const ushort*)nullptr, perm,
                                   e_ws, sdst_p, ssrc_p, Wt1, bc1, xo);
    stats_kernel<<<80, 256, 0, stream>>>(xo, sacc);
    apply_kernel<true><<<nApply, 256, 0, stream>>>(xo, sacc, g1, bt1, out, xb);

    // ---- layers 2..10: NCH=6, ET=64 (double tile); 3 blocks/CU, grid 768 ----
    for (int i = 0; i < 9; ++i) {
        msg_mfma_kernel<6, 64, false>
            <<<768, 256, 0, stream>>>(xb, (const float*)nullptr, e_ws, (const int*)nullptr,
                                      e_ws, sdst_p, ssrc_p,
                                      Wtk + (size_t)i * 128 * 192,
                                      bck + (size_t)i * 128, xo);
        stats_kernel<<<80, 256, 0, stream>>>(xo, sacc + (i + 1) * 128);
        apply_kernel<false><<<nApply, 256, 0, stream>>>(xo, sacc + (i + 1) * 128,
                                                        gam + (size_t)i * HID,
                                                        bet + (size_t)i * HID, out, xb);
    }
}

// Round 12
// 526.373 us; speedup vs baseline: 1.2435x; 1.2435x over previous
//
#include <hip/hip_runtime.h>
#include <hip/hip_bf16.h>
#include <math.h>

#define N_NODES 20000
#define N_EDGES 320000
#define HID 50
#define XS 64     // row stride (ushorts) for all bf16 node/edge state -> 128 B, 16B-aligned

typedef short bf16x8 __attribute__((ext_vector_type(8)));
typedef float f32x4 __attribute__((ext_vector_type(4)));

__device__ inline ushort f2bf(float f) {
    __hip_bfloat16 h = __float2bfloat16(f);
    union { __hip_bfloat16 h; ushort u; } c; c.h = h; return c.u;
}
__device__ inline uint pack2(float a, float b) {
    return (uint)f2bf(a) | ((uint)f2bf(b) << 16);
}

// LDS-only barrier: waits LDS ops, does NOT drain vmcnt -> global loads,
// stores and atomics stay in flight across tiles (T4). sched_barrier(0)
// fences the machine scheduler on both sides (rule #18).
__device__ inline void lds_barrier() {
    asm volatile("s_waitcnt lgkmcnt(0)" ::: "memory");
    __builtin_amdgcn_sched_barrier(0);
    __builtin_amdgcn_s_barrier();
    __builtin_amdgcn_sched_barrier(0);
    asm volatile("" ::: "memory");
}

// ---------------------------------------------------------------------------
// Edge sorting by dst: histogram -> single-block scan -> atomic scatter.
// ---------------------------------------------------------------------------
__global__ __launch_bounds__(256) void hist_kernel(const int* __restrict__ dst, int* __restrict__ cnt) {
    const int e = blockIdx.x * 256 + threadIdx.x;
    if (e < N_EDGES) atomicAdd(&cnt[dst[e]], 1);
}

__global__ __launch_bounds__(1024) void scan_kernel(const int* __restrict__ cnt, int* __restrict__ offs) {
    __shared__ int part[1024];
    const int t = threadIdx.x;
    int loc[20]; int s = 0;
    #pragma unroll
    for (int i = 0; i < 20; ++i) {
        const int idx = t * 20 + i;
        const int v = (idx < N_NODES) ? cnt[idx] : 0;
        loc[i] = s; s += v;
    }
    part[t] = s; __syncthreads();
    for (int off = 1; off < 1024; off <<= 1) {
        const int v = (t >= off) ? part[t - off] : 0;
        __syncthreads();
        part[t] += v;
        __syncthreads();
    }
    const int ex = (t > 0) ? part[t - 1] : 0;
    #pragma unroll
    for (int i = 0; i < 20; ++i) {
        const int idx = t * 20 + i;
        if (idx < N_NODES) offs[idx] = ex + loc[i];
    }
}

__global__ __launch_bounds__(256) void scatter_kernel(const int* __restrict__ src, const int* __restrict__ dst,
        int* __restrict__ offs, int* __restrict__ perm,
        int* __restrict__ sdst_p, int* __restrict__ ssrc_p) {
    const int e = blockIdx.x * 256 + threadIdx.x;
    if (e >= N_EDGES) return;
    const int d = dst[e];
    const int pos = atomicAdd(&offs[d], 1);
    perm[pos] = e;
    sdst_p[pos] = d;
    ssrc_p[pos] = src[e];
}

__global__ __launch_bounds__(256) void xconv_kernel(const float* __restrict__ x, ushort* __restrict__ xb1) {
    const int i = blockIdx.x * 256 + threadIdx.x;
    if (i < N_NODES * 64) xb1[i] = f2bf(x[i]);   // XS==64 == feature count: dense
}

// ---------------------------------------------------------------------------
// Build W^T bf16 [128][Kpad], section layout: orig W rows [0,F) -> k 0..,
// [F,2F) -> k 64.., [2F,2F+FE) -> k 128..; other k rows are ZERO.
// cols 0..49 = Wm, cols 64..113 = We, rest 0. bc[128] = fused bias.
// ---------------------------------------------------------------------------
__global__ __launch_bounds__(256) void prep_w_kernel(
    const float* __restrict__ Wm, const float* __restrict__ We,
    const float* __restrict__ bm, const float* __restrict__ be,
    ushort* __restrict__ Wt, float* __restrict__ bc, int F, int FE, int Kpad)
{
    const int l = blockIdx.y;
    const int K = 2 * F + FE;
    const float* Wm_l = Wm + (size_t)l * K * HID;
    const float* We_l = We + (size_t)l * K * HID;
    const float* bm_l = bm + (size_t)l * HID;
    const float* be_l = be + (size_t)l * HID;
    ushort* Wt_l = Wt + (size_t)l * 128 * Kpad;
    float*  bc_l = bc + (size_t)l * 128;
    for (int idx = blockIdx.x * 256 + threadIdx.x; idx < 128 * Kpad; idx += gridDim.x * 256) {
        const int c = idx / Kpad;
        const int k = idx - c * Kpad;
        int r = -1;
        if (k < 64)       { if (k < F)        r = k; }
        else if (k < 128) { if (k - 64 < F)   r = F + (k - 64); }
        else              { if (k - 128 < FE) r = 2 * F + (k - 128); }
        float v = 0.f;
        if (r >= 0) {
            if (c < HID)                      v = Wm_l[(size_t)r * HID + c];
            else if (c >= 64 && c < 64 + HID) v = We_l[(size_t)r * HID + (c - 64)];
        }
        Wt_l[(size_t)c * Kpad + k] = f2bf(v);
        if (k == 0) {
            float b = 0.f;
            if (c < HID)                      b = bm_l[c];
            else if (c >= 64 && c < 64 + HID) b = be_l[c - 64];
            bc_l[c] = b;
        }
    }
}

// ---------------------------------------------------------------------------
// Persistent pipelined MFMA message+edge-update kernel.
// Per tile: compute -> out->LDS -> [lds_barrier] -> write_stage(t+G)
//           -> issue(t+2G) -> e-stores -> seg-sum atomics -> [lds_barrier].
// Barriers wait ONLY on lgkmcnt: vmem (gathers/stores/atomics) never drains
// inside the loop; atomics retire under the next tile's compute.
// ---------------------------------------------------------------------------
template<int NCH, bool L1>
__global__ __launch_bounds__(256, L1 ? 1 : 4) void msg_mfma_kernel(
    const ushort* __restrict__ xb,       // bf16 node features, row stride XS
    const float*  __restrict__ ea,       // L1: fp32 [E][112] (original order)
    const ushort* __restrict__ ein,      // !L1: bf16 [E][XS] (sorted order)
    const int*    __restrict__ perm,     // L1: sorted -> original edge id
    ushort* __restrict__ eout,           // bf16 [E][XS] (sorted order)
    const int* __restrict__ sdst_idx, const int* __restrict__ ssrc_idx,  // sorted
    const ushort* __restrict__ Wt,       // bf16 [128][NCH*32]
    const float* __restrict__ bc,        // [128]
    float* __restrict__ xo)
{
    constexpr int KPAD = NCH * 32;       // ushorts per h row
    constexpr int KPS  = KPAD + 8;       // +16B pad (row stride still 16B-aligned)
    constexpr int NT   = N_EDGES / 32;

    __shared__ __align__(16) ushort hl[32 * KPS];
    __shared__ __align__(16) float  xol[32 * 52];
    __shared__ __align__(16) ushort epack[32 * 72];
    __shared__ int sdst_s[2][32];
    __shared__ int segs[34];
    __shared__ int nseg_s;

    const int t = threadIdx.x;
    const int lane = t & 63, w = t >> 6;
    const int r = t >> 3, ch0 = t & 7;         // staging row / 16B-chunk
    const int row16 = lane & 15, g = lane >> 4;
    const int G = gridDim.x;

    // staged registers (data for a future tile)
    int sd, ss, pm;
    bf16x8 Rd, Rs, Re;
    float4 P0a, P0b, P1a, P1b;

    auto issue = [&](int tl) {
        const int eb = tl * 32;
        sd = sdst_idx[eb + r];
        ss = ssrc_idx[eb + r];
        Rd = *(const bf16x8*)(xb + (size_t)sd * XS + ch0 * 8);
        Rs = *(const bf16x8*)(xb + (size_t)ss * XS + ch0 * 8);
        if constexpr (L1) {
            pm = perm[eb + r];
            const float* pe = ea + (size_t)pm * 112;
            P0a = *(const float4*)(pe + 8 * ch0);
            P0b = *(const float4*)(pe + 8 * ch0 + 4);
            if (ch0 < 6) {
                P1a = *(const float4*)(pe + 8 * (ch0 + 8));
                P1b = *(const float4*)(pe + 8 * (ch0 + 8) + 4);
            }
        } else {
            Re = *(const bf16x8*)(ein + ((size_t)eb + r) * XS + ch0 * 8);
        }
    };

    auto write_stage = [&](int par) {
        *(bf16x8*)&hl[r * KPS + ch0 * 8]      = Rd;
        *(bf16x8*)&hl[r * KPS + 64 + ch0 * 8] = Rs;
        if constexpr (L1) {
            union { bf16x8 v; uint u[4]; } c0;
            c0.u[0] = pack2(P0a.x, P0a.y); c0.u[1] = pack2(P0a.z, P0a.w);
            c0.u[2] = pack2(P0b.x, P0b.y); c0.u[3] = pack2(P0b.z, P0b.w);
            *(bf16x8*)&hl[r * KPS + 128 + ch0 * 8] = c0.v;
            if (ch0 < 6) {
                union { bf16x8 v; uint u[4]; } c1;
                c1.u[0] = pack2(P1a.x, P1a.y); c1.u[1] = pack2(P1a.z, P1a.w);
                c1.u[2] = pack2(P1b.x, P1b.y); c1.u[3] = pack2(P1b.z, P1b.w);
                *(bf16x8*)&hl[r * KPS + 192 + ch0 * 8] = c1.v;
            } else {
                *(bf16x8*)&hl[r * KPS + 192 + ch0 * 8] = (bf16x8){0,0,0,0,0,0,0,0};
            }
        } else {
            *(bf16x8*)&hl[r * KPS + 128 + ch0 * 8] = Re;
        }
        if (ch0 == 0) sdst_s[par][r] = sd;
    };

    int tile = blockIdx.x;
    if (tile >= NT) return;

    const int colA = (2 * w) * 16 + row16;
    const int colB = colA + 16;
    const float bA = bc[colA], bB = bc[colB];
    const ushort* wpA = Wt + (size_t)colA * KPAD + 8 * g;
    const ushort* wpB = Wt + (size_t)colB * KPAD + 8 * g;

    // hoisted W fragments for the K150 layers (48 VGPR at NCH=6)
    bf16x8 BfA[NCH], BfB[NCH];
    if constexpr (!L1) {
        #pragma unroll
        for (int c = 0; c < NCH; ++c) {
            BfA[c] = *(const bf16x8*)(wpA + c * 32);
            BfB[c] = *(const bf16x8*)(wpB + c * 32);
        }
    }

    // prologue: stage first tile; issue loads for the second
    issue(tile);
    write_stage(0);
    if (tile + G < NT) issue(tile + G);
    __syncthreads();

    int par = 0;
    for (; tile < NT; tile += G) {
        // ---- compute: each wave owns col-tiles {2w, 2w+1} over 2 M-tiles ----
        f32x4 accA0 = (f32x4){bA, bA, bA, bA}, accA1 = accA0;
        f32x4 accB0 = (f32x4){bB, bB, bB, bB}, accB1 = accB0;
        #pragma unroll
        for (int c = 0; c < NCH; ++c) {
            const bf16x8 a0 = *(const bf16x8*)&hl[row16 * KPS + c * 32 + 8 * g];
            const bf16x8 a1 = *(const bf16x8*)&hl[(16 + row16) * KPS + c * 32 + 8 * g];
            bf16x8 B0, B1;
            if constexpr (L1) {
                B0 = *(const bf16x8*)(wpA + c * 32);
                B1 = *(const bf16x8*)(wpB + c * 32);
            } else {
                B0 = BfA[c];
                B1 = BfB[c];
            }
            accA0 = __builtin_amdgcn_mfma_f32_16x16x32_bf16(a0, B0, accA0, 0, 0, 0);
            accA1 = __builtin_amdgcn_mfma_f32_16x16x32_bf16(a1, B0, accA1, 0, 0, 0);
            accB0 = __builtin_amdgcn_mfma_f32_16x16x32_bf16(a0, B1, accB0, 0, 0, 0);
            accB1 = __builtin_amdgcn_mfma_f32_16x16x32_bf16(a1, B1, accB1, 0, 0, 0);
        }

        // ---- write outputs to LDS scratch ----
        if (w < 2) {
            #pragma unroll
            for (int rr = 0; rr < 4; ++rr) {
                if (colA < HID) {
                    xol[(4 * g + rr) * 52 + colA]      = accA0[rr];
                    xol[(16 + 4 * g + rr) * 52 + colA] = accA1[rr];
                }
                if (colB < HID) {
                    xol[(4 * g + rr) * 52 + colB]      = accB0[rr];
                    xol[(16 + 4 * g + rr) * 52 + colB] = accB1[rr];
                }
            }
        } else {
            const int lcA = colA - 64, lcB = colB - 64;
            #pragma unroll
            for (int rr = 0; rr < 4; ++rr) {
                epack[(4 * g + rr) * 72 + lcA]      = f2bf(accA0[rr]);
                epack[(16 + 4 * g + rr) * 72 + lcA] = f2bf(accA1[rr]);
                epack[(4 * g + rr) * 72 + lcB]      = f2bf(accB0[rr]);
                epack[(16 + 4 * g + rr) * 72 + lcB] = f2bf(accB1[rr]);
            }
        }

        // ---- wave 0: segment boundaries of sorted dst ----
        if (w == 0) {
            const int l31 = lane & 31;
            const int dl  = sdst_s[par][l31];
            const int dp  = sdst_s[par][l31 > 0 ? l31 - 1 : 0];
            const bool flag = (l31 == 0) || (dl != dp);
            const unsigned long long bal = __ballot(flag) & 0xFFFFFFFFull;
            if (lane < 32 && flag)
                segs[__popcll(bal & ((1ull << l31) - 1ull))] = l31;
            if (lane == 0) {
                const int ns = __popcll(bal);
                nseg_s = ns;
                segs[ns] = 32;
            }
        }
        lds_barrier();   // B1: xol/epack/segs visible; hl reads done (LDS only)

        // ---- pipeline FIRST: ds_writes; staged regs are a full phase old ----
        if (tile + G < NT)     write_stage(par ^ 1);
        if (tile + 2 * G < NT) issue(tile + 2 * G);

        // ---- e-state full-row stores (all 64 cols; 50..63 are exact 0) ----
        {
            const int4 v = *(const int4*)&epack[r * 72 + ch0 * 8];
            *(int4*)&eout[((size_t)tile * 32 + r) * XS + ch0 * 8] = v;
        }
        // ---- segmented sum -> atomics (retire in next tile's shadow) ----
        const int ns = nseg_s;
        for (int idx = t; idx < ns * HID; idx += 256) {
            const int s = idx / HID, col = idx - s * HID;
            const int a0 = segs[s], b0 = segs[s + 1];
            float s0 = 0.f, s1 = 0.f, s2 = 0.f, s3 = 0.f;
            int rr = a0;
            for (; rr + 4 <= b0; rr += 4) {
                s0 += xol[(rr + 0) * 52 + col];
                s1 += xol[(rr + 1) * 52 + col];
                s2 += xol[(rr + 2) * 52 + col];
                s3 += xol[(rr + 3) * 52 + col];
            }
            for (; rr < b0; ++rr) s0 += xol[rr * 52 + col];
            atomicAdd(&xo[(size_t)sdst_s[par][a0] * HID + col], (s0 + s1) + (s2 + s3));
        }
        lds_barrier();   // B2: hl now holds tile+G (LDS only; vmem stays in flight)
        par ^= 1;
    }
}

// coalesced column stats: 80 blocks, contiguous 12500-elem span each,
// 250 threads x 50 iters (stride 250); partials -> atomics into sacc slot
__global__ __launch_bounds__(256) void stats_kernel(const float* __restrict__ xo,
                                                    float* __restrict__ sacc)
{
    __shared__ float sp[5][HID], sq[5][HID];
    const int t = threadIdx.x;
    if (t < 250) {
        float s = 0.f, q = 0.f;
        const size_t base = (size_t)blockIdx.x * 12500 + t;
        #pragma unroll
        for (int it = 0; it < 50; ++it) {
            const float v = xo[base + it * 250];
            s += v; q += v * v;
        }
        sp[t / HID][t % HID] = s;
        sq[t / HID][t % HID] = q;
    }
    __syncthreads();
    if (t < HID) {
        float s = 0.f, q = 0.f;
        #pragma unroll
        for (int p = 0; p < 5; ++p) { s += sp[p][t]; q += sq[p][t]; }
        atomicAdd(&sacc[t], s);
        atomicAdd(&sacc[HID + t], q);
    }
}

// BN(train) + ELU + residual; maintains bf16 mirror xb; zeroes xo for next layer
template<bool FIRST>
__global__ __launch_bounds__(256) void apply_kernel(float* __restrict__ xo,
    const float* __restrict__ sacc,
    const float* __restrict__ g, const float* __restrict__ b,
    float* __restrict__ cur, ushort* __restrict__ xb)
{
    const int i = blockIdx.x * 256 + threadIdx.x;
    if (i >= N_NODES * HID) return;
    const int c = i % HID;
    const float inv = 1.f / (float)N_NODES;
    const float mu = sacc[c] * inv;
    const float var = sacc[HID + c] * inv - mu * mu;
    const float z = (xo[i] - mu) * rsqrtf(var + 1e-5f) * g[c] + b[c];
    xo[i] = 0.f;                               // ready for next layer's atomics
    const float a = (z > 0.f) ? z : expm1f(z);
    const float nc = FIRST ? a : (cur[i] + a);
    cur[i] = nc;
    xb[(size_t)(i / HID) * XS + c] = f2bf(nc);
}

extern "C" void kernel_launch(void* const* d_in, const int* in_sizes, int n_in,
                              void* d_out, int out_size, void* d_ws, size_t ws_size,
                              hipStream_t stream)
{
    const float* x    = (const float*)d_in[0];
    const int*   ei   = (const int*)  d_in[1];
    const float* ea   = (const float*)d_in[2];
    const float* W1m  = (const float*)d_in[4];
    const float* b1m  = (const float*)d_in[5];
    const float* W1e  = (const float*)d_in[6];
    const float* b1e  = (const float*)d_in[7];
    const float* g1   = (const float*)d_in[8];
    const float* bt1  = (const float*)d_in[9];
    const float* Wm   = (const float*)d_in[10];
    const float* bm   = (const float*)d_in[11];
    const float* We   = (const float*)d_in[12];
    const float* be   = (const float*)d_in[13];
    const float* gam  = (const float*)d_in[14];
    const float* bet  = (const float*)d_in[15];

    float* out = (float*)d_out;

    char* ws = (char*)d_ws;
    ushort* e_ws   = (ushort*)(ws + 0);                      // [E][64] bf16   40,960,000
    float*  xo     = (float*) (ws + 40960000);               // [20000][50]     4,000,000
    float*  sacc   = (float*) (ws + 44960000);               // [10][128]           5,120
    ushort* Wt1    = (ushort*)(ws + 44965120);               // [128][256]         65,536
    float*  bc1    = (float*) (ws + 45030656);               // [128]                 512
    ushort* Wtk    = (ushort*)(ws + 45031168);               // [9][128][192]     442,368
    float*  bck    = (float*) (ws + 45473536);               // [9][128] + pad      5,120
    ushort* xb1    = (ushort*)(ws + 45478656);               // [20000][64]     2,560,000
    ushort* xb     = (ushort*)(ws + 48038656);               // [20000][64]     2,560,000
    int*    cnt    = (int*)   (ws + 50598656);               // [20000]            80,000
    int*    offs   = (int*)   (ws + 50678656);               // [20000]            80,000
    int*    perm   = (int*)   (ws + 50758656);               // [E]             1,280,000
    int*    sdst_p = (int*)   (ws + 52038656);               // [E]             1,280,000
    int*    ssrc_p = (int*)   (ws + 53318656);               // [E]             1,280,000

    const int* srcs = ei;
    const int* dsts = ei + N_EDGES;
    const int nApply = (N_NODES * HID + 255) / 256;

    // ---- one-time prep: sanitize state, sort edges by dst, convert, transpose ----
    hipMemsetAsync(xo, 0, 4005120, stream);                  // xo + sacc
    hipMemsetAsync(xb, 0, 2560000, stream);                  // pad cols of xb
    hipMemsetAsync(cnt, 0, N_NODES * sizeof(int), stream);
    hist_kernel<<<1250, 256, 0, stream>>>(dsts, cnt);
    scan_kernel<<<1, 1024, 0, stream>>>(cnt, offs);
    scatter_kernel<<<1250, 256, 0, stream>>>(srcs, dsts, offs, perm, sdst_p, ssrc_p);
    xconv_kernel<<<5000, 256, 0, stream>>>(x, xb1);
    prep_w_kernel<<<dim3(128, 1), 256, 0, stream>>>(W1m, W1e, b1m, b1e, Wt1, bc1, 64, 112, 256);
    prep_w_kernel<<<dim3(128, 9), 256, 0, stream>>>(Wm, We, bm, be, Wtk, bck, 50, 50, 192);

    // ---- layer 1: NCH=8 (K=256), ea fp32 via perm; no reg cap (spill-free) ----
    msg_mfma_kernel<8, true>
        <<<1280, 256, 0, stream>>>(xb1, ea, (const ushort*)nullptr, perm,
                                   e_ws, sdst_p, ssrc_p, Wt1, bc1, xo);
    stats_kernel<<<80, 256, 0, stream>>>(xo, sacc);
    apply_kernel<true><<<nApply, 256, 0, stream>>>(xo, sacc, g1, bt1, out, xb);

    // ---- layers 2..10: NCH=6 (K=192), e bf16 in-place; 4 blocks/CU ----
    for (int i = 0; i < 9; ++i) {
        msg_mfma_kernel<6, false>
            <<<1024, 256, 0, stream>>>(xb, (const float*)nullptr, e_ws, (const int*)nullptr,
                                       e_ws, sdst_p, ssrc_p,
                                       Wtk + (size_t)i * 128 * 192,
                                       bck + (size_t)i * 128, xo);
        stats_kernel<<<80, 256, 0, stream>>>(xo, sacc + (i + 1) * 128);
        apply_kernel<false><<<nApply, 256, 0, stream>>>(xo, sacc + (i + 1) * 128,
                                                        gam + (size_t)i * HID,
                                                        bet + (size_t)i * HID, out, xb);
    }
}